// Round 1
// baseline (1102.901 us; speedup 1.0000x reference)
//
#include <hip/hip_runtime.h>
#include <hip/hip_bf16.h>

// Problem: E=8 experts, C=4096 tokens/expert, M=1024, H=4096, O=1024, fp32.
//   y   = relu(x @ fc1_w + fc1_b)    [E,C,M]@[E,M,H]
//   out = y @ fc2_w + fc2_b          [E,C,H]@[E,H,O]
// Strategy: convert to bf16, pre-transpose weights to [N,K], run m97-style
// 128x128 MFMA GEMM with global_load_lds width-16 staging. y kept bf16.

#define BM 128
#define BN 128
#define BK 32

typedef __attribute__((ext_vector_type(8))) short short8;   // 8 bf16 = 4 VGPRs
typedef __attribute__((ext_vector_type(4))) float f32x4;

typedef const __attribute__((address_space(1))) void GV;
typedef __attribute__((address_space(3))) void LV;

__device__ inline ushort f2bf_rne(float f) {
    union { float f; unsigned u; } v; v.f = f;
    unsigned u = v.u;
    u += 0x7FFFu + ((u >> 16) & 1u);   // round-to-nearest-even
    return (ushort)(u >> 16);
}

// ---------------- elementwise fp32 -> bf16 convert ----------------
__global__ __launch_bounds__(256) void convert_bf16(
    const float* __restrict__ in, ushort* __restrict__ out, long n) {
    long i = ((long)blockIdx.x * 256 + threadIdx.x) * 4;
    if (i + 3 >= n) return;
    float4 v = *(const float4*)&in[i];
    ushort4 o;
    o.x = f2bf_rne(v.x); o.y = f2bf_rne(v.y);
    o.z = f2bf_rne(v.z); o.w = f2bf_rne(v.w);
    *(ushort4*)&out[i] = o;
}

// ------------- [K,N] fp32 -> [N,K] bf16 tiled transpose -------------
// in: per-expert R x Cn (row-major), out: per-expert Cn x R (row-major bf16)
__global__ __launch_bounds__(256) void transpose_convert(
    const float* __restrict__ in, ushort* __restrict__ out, int R, int Cn) {
    __shared__ float tile[64][65];          // +1 pad: conflict-free col reads
    const int e  = blockIdx.z;
    const float* ine  = in  + (size_t)e * R * Cn;
    ushort*      oute = out + (size_t)e * R * Cn;
    const int r0 = blockIdx.y * 64;         // input row block (K dim)
    const int c0 = blockIdx.x * 64;         // input col block (N dim)
    const int tr = threadIdx.x >> 4;        // 0..15
    const int tc = (threadIdx.x & 15) * 4;  // 0..60
#pragma unroll
    for (int i = 0; i < 4; ++i) {
        int row = i * 16 + tr;
        float4 v = *(const float4*)&ine[(size_t)(r0 + row) * Cn + c0 + tc];
        tile[row][tc + 0] = v.x; tile[row][tc + 1] = v.y;
        tile[row][tc + 2] = v.z; tile[row][tc + 3] = v.w;
    }
    __syncthreads();
#pragma unroll
    for (int i = 0; i < 4; ++i) {
        int oc = i * 16 + tr;               // output row (N dim)
        ushort4 o;
        o.x = f2bf_rne(tile[tc + 0][oc]);
        o.y = f2bf_rne(tile[tc + 1][oc]);
        o.z = f2bf_rne(tile[tc + 2][oc]);
        o.w = f2bf_rne(tile[tc + 3][oc]);
        *(ushort4*)&oute[(size_t)(c0 + oc) * R + r0 + tc] = o;
    }
}

// ---------------- m97-style bf16 GEMM, B^T input ----------------
// A: [4096, K] bf16, Bt: [N, K] bf16, per-expert via blockIdx.z.
// RELU_BF16_OUT: bias+relu, bf16 out (GEMM1). else: bias, fp32 out (GEMM2).
template <bool RELU_BF16_OUT>
__global__ __launch_bounds__(256, 2) void gemm_bt(
    const ushort* __restrict__ A, const ushort* __restrict__ Bt,
    const float* __restrict__ bias, void* __restrict__ out,
    int K, int N) {
    __shared__ ushort As[BM * BK];   // [row][k], 8 KB
    __shared__ ushort Bs[BN * BK];   // [n][k],   8 KB

    const int e  = blockIdx.z;
    const int Crows = 4096;
    const ushort* Ae = A  + (size_t)e * Crows * K;
    const ushort* Be = Bt + (size_t)e * N * K;
    const float*  be = bias + (size_t)e * N;

    const int m0 = blockIdx.y * BM;
    const int n0 = blockIdx.x * BN;

    const int t    = threadIdx.x;
    const int lane = t & 63;
    const int wave = t >> 6;
    const int wm   = (wave >> 1) * 64;
    const int wn   = (wave & 1) * 64;
    const int quad = lane >> 4;      // 0..3
    const int lrow = lane & 15;      // 0..15

    // staging pointers: i covers 512 16B-chunks (2 rounds x 256 threads)
    const int i0 = t, i1 = t + 256;
    const ushort* gA0 = Ae + (size_t)(m0 + (i0 >> 2)) * K + (i0 & 3) * 8;
    const ushort* gA1 = Ae + (size_t)(m0 + (i1 >> 2)) * K + (i1 & 3) * 8;
    const ushort* gB0 = Be + (size_t)(n0 + (i0 >> 2)) * K + (i0 & 3) * 8;
    const ushort* gB1 = Be + (size_t)(n0 + (i1 >> 2)) * K + (i1 & 3) * 8;
    ushort* lA0 = &As[i0 * 8];
    ushort* lA1 = &As[i1 * 8];
    ushort* lB0 = &Bs[i0 * 8];
    ushort* lB1 = &Bs[i1 * 8];

    f32x4 acc[4][4] = {};

    for (int k0 = 0; k0 < K; k0 += BK) {
        __builtin_amdgcn_global_load_lds((GV*)gA0, (LV*)lA0, 16, 0, 0);
        __builtin_amdgcn_global_load_lds((GV*)gA1, (LV*)lA1, 16, 0, 0);
        __builtin_amdgcn_global_load_lds((GV*)gB0, (LV*)lB0, 16, 0, 0);
        __builtin_amdgcn_global_load_lds((GV*)gB1, (LV*)lB1, 16, 0, 0);
        gA0 += BK; gA1 += BK; gB0 += BK; gB1 += BK;
        __syncthreads();   // drains vmcnt before barrier

        short8 a[4], b[4];
#pragma unroll
        for (int i = 0; i < 4; ++i) {
            a[i] = *(const short8*)&As[(wm + i * 16 + lrow) * BK + quad * 8];
            b[i] = *(const short8*)&Bs[(wn + i * 16 + lrow) * BK + quad * 8];
        }
#pragma unroll
        for (int mi = 0; mi < 4; ++mi)
#pragma unroll
            for (int ni = 0; ni < 4; ++ni)
                acc[mi][ni] = __builtin_amdgcn_mfma_f32_16x16x32_bf16(
                    a[mi], b[ni], acc[mi][ni], 0, 0, 0);
        __syncthreads();
    }

    // epilogue: C/D layout col=lane&15, row=quad*4+reg [m89/m91 verified]
#pragma unroll
    for (int mi = 0; mi < 4; ++mi) {
#pragma unroll
        for (int ni = 0; ni < 4; ++ni) {
            const int gn = n0 + wn + ni * 16 + lrow;
            const float bv = be[gn];
#pragma unroll
            for (int r = 0; r < 4; ++r) {
                const int gm = m0 + wm + mi * 16 + quad * 4 + r;
                float v = acc[mi][ni][r] + bv;
                if (RELU_BF16_OUT) {
                    v = fmaxf(v, 0.f);
                    ((ushort*)out)[(size_t)e * Crows * N + (size_t)gm * N + gn] =
                        f2bf_rne(v);
                } else {
                    ((float*)out)[(size_t)e * Crows * N + (size_t)gm * N + gn] = v;
                }
            }
        }
    }
}

extern "C" void kernel_launch(void* const* d_in, const int* in_sizes, int n_in,
                              void* d_out, int out_size, void* d_ws, size_t ws_size,
                              hipStream_t stream) {
    const int E = 8, C = 4096, M = 1024, H = 4096, O = 1024;
    const float* x  = (const float*)d_in[0];
    const float* w1 = (const float*)d_in[1];
    const float* b1 = (const float*)d_in[2];
    const float* w2 = (const float*)d_in[3];
    const float* b2 = (const float*)d_in[4];
    float* out = (float*)d_out;

    // workspace: [x_bf 67MB][w1t 67MB][y 268MB]; w2t aliases w1t (used after GEMM1)
    ushort* x_bf = (ushort*)d_ws;                       // E*C*M
    ushort* w1t  = x_bf + (size_t)E * C * M;            // E*H*M
    ushort* w2t  = w1t;                                 // E*O*H (alias, after GEMM1)
    ushort* y_bf = w1t + (size_t)E * M * H;             // E*C*H

    const long nx = (long)E * C * M;
    convert_bf16<<<(nx / 4 + 255) / 256, 256, 0, stream>>>(x, x_bf, nx);
    transpose_convert<<<dim3(H / 64, M / 64, E), 256, 0, stream>>>(w1, w1t, M, H);
    gemm_bt<true><<<dim3(H / 128, C / 128, E), 256, 0, stream>>>(
        x_bf, w1t, b1, (void*)y_bf, M, H);
    transpose_convert<<<dim3(O / 64, H / 64, E), 256, 0, stream>>>(w2, w2t, H, O);
    gemm_bt<false><<<dim3(O / 128, C / 128, E), 256, 0, stream>>>(
        y_bf, w2t, b2, (void*)out, H, O);
}

// Round 2
// 1034.498 us; speedup vs baseline: 1.0661x; 1.0661x over previous
//
#include <hip/hip_runtime.h>
#include <hip/hip_bf16.h>

// E=8, C=4096, M=1024, H=4096, O=1024, fp32 in/out.
//   y   = relu(x @ fc1_w + fc1_b);  out = y @ fc2_w + fc2_b
// bf16 MFMA GEMM (m97 structure) + R2: XCD-aware 8x8 supertile swizzle to cut
// HBM re-fetch (R1 counters: FETCH 1.26GB vs 134MB inputs -> memory-bound).

#define BM 128
#define BN 128
#define BK 32

typedef __attribute__((ext_vector_type(8))) short short8;   // 8 bf16 = 4 VGPRs
typedef __attribute__((ext_vector_type(4))) float f32x4;

typedef const __attribute__((address_space(1))) void GV;
typedef __attribute__((address_space(3))) void LV;

__device__ inline ushort f2bf_rne(float f) {
    union { float f; unsigned u; } v; v.f = f;
    unsigned u = v.u;
    u += 0x7FFFu + ((u >> 16) & 1u);   // round-to-nearest-even
    return (ushort)(u >> 16);
}

// ---------------- elementwise fp32 -> bf16 convert, 8 elem/thread ----------------
__global__ __launch_bounds__(256) void convert_bf16(
    const float* __restrict__ in, ushort* __restrict__ out, long n) {
    long i = ((long)blockIdx.x * 256 + threadIdx.x) * 8;
    if (i + 7 >= n) return;
    float4 v0 = *(const float4*)&in[i];
    float4 v1 = *(const float4*)&in[i + 4];
    short8 o;
    o[0] = f2bf_rne(v0.x); o[1] = f2bf_rne(v0.y);
    o[2] = f2bf_rne(v0.z); o[3] = f2bf_rne(v0.w);
    o[4] = f2bf_rne(v1.x); o[5] = f2bf_rne(v1.y);
    o[6] = f2bf_rne(v1.z); o[7] = f2bf_rne(v1.w);
    *(short8*)&out[i] = o;
}

// ------------- [K,N] fp32 -> [N,K] bf16 tiled transpose, 16B stores -------------
__global__ __launch_bounds__(256) void transpose_convert(
    const float* __restrict__ in, ushort* __restrict__ out, int R, int Cn) {
    __shared__ float tile[64][65];          // pad: phase2 is 2-way (free, m136)
    const int e  = blockIdx.z;
    const float* ine  = in  + (size_t)e * R * Cn;
    ushort*      oute = out + (size_t)e * R * Cn;
    const int r0 = blockIdx.y * 64;         // input row block (K dim)
    const int c0 = blockIdx.x * 64;         // input col block (N dim)
    const int t  = threadIdx.x;
    // load: 1024 float4-chunks of the 64x64 tile, 4/thread, row-coalesced
#pragma unroll
    for (int i = 0; i < 4; ++i) {
        int idx = i * 256 + t;
        int ir  = idx >> 4;
        int icc = (idx & 15) * 4;
        float4 v = *(const float4*)&ine[(size_t)(r0 + ir) * Cn + c0 + icc];
        tile[ir][icc + 0] = v.x; tile[ir][icc + 1] = v.y;
        tile[ir][icc + 2] = v.z; tile[ir][icc + 3] = v.w;
    }
    __syncthreads();
    // store: 512 short8-chunks (16B), 2/thread, k-coalesced
#pragma unroll
    for (int i = 0; i < 2; ++i) {
        int idx = i * 256 + t;
        int ic  = idx >> 3;            // output row  (N dim)
        int ir0 = (idx & 7) * 8;       // output cols (K dim), 8 consecutive
        short8 o;
#pragma unroll
        for (int j = 0; j < 8; ++j) o[j] = f2bf_rne(tile[ir0 + j][ic]);
        *(short8*)&oute[(size_t)(c0 + ic) * R + r0 + ir0] = o;
    }
}

// ---------------- bf16 GEMM, B^T input, XCD supertile swizzle ----------------
// A: [E,4096,K] bf16, Bt: [E,N,K] bf16. 1D grid of GX*GY*8 blocks.
// Swizzle: pid%8 = XCD (dispatch round-robin heuristic); each XCD walks 8x8
// block supertiles (8 A-stripes + 8 B-stripes ~= 4MB = one L2) contiguously.
template <bool RELU_BF16_OUT, int GX, int GY, int K, int N>
__global__ __launch_bounds__(256, 2) void gemm_bt(
    const ushort* __restrict__ A, const ushort* __restrict__ Bt,
    const float* __restrict__ bias, void* __restrict__ out) {
    __shared__ ushort As[BM * BK];   // 8 KB
    __shared__ ushort Bs[BN * BK];   // 8 KB

    constexpr int TOTAL   = GX * GY * 8;            // 8 experts
    constexpr int ST_PER_E = (GY / 8) * (GX / 8);   // supertiles per expert
    constexpr int ST_PER_X = TOTAL / 8 / 64;        // supertiles per XCD

    const int pid   = blockIdx.x;
    const int xcd   = pid & 7;
    const int local = pid >> 3;
    const int st    = xcd * ST_PER_X + (local >> 6);
    const int within = local & 63;
    const int e   = st / ST_PER_E;
    const int str = st % ST_PER_E;
    const int stm = str / (GX / 8);
    const int stn = str % (GX / 8);
    const int by  = stm * 8 + (within & 7);
    const int bx  = stn * 8 + (within >> 3);

    const int Crows = 4096;
    const ushort* Ae = A  + (size_t)e * Crows * K;
    const ushort* Be = Bt + (size_t)e * N * K;
    const float*  be = bias + (size_t)e * N;

    const int m0 = by * BM;
    const int n0 = bx * BN;

    const int t    = threadIdx.x;
    const int lane = t & 63;
    const int wave = t >> 6;
    const int wm   = (wave >> 1) * 64;
    const int wn   = (wave & 1) * 64;
    const int quad = lane >> 4;
    const int lrow = lane & 15;

    const int i0 = t, i1 = t + 256;
    const ushort* gA0 = Ae + (size_t)(m0 + (i0 >> 2)) * K + (i0 & 3) * 8;
    const ushort* gA1 = Ae + (size_t)(m0 + (i1 >> 2)) * K + (i1 & 3) * 8;
    const ushort* gB0 = Be + (size_t)(n0 + (i0 >> 2)) * K + (i0 & 3) * 8;
    const ushort* gB1 = Be + (size_t)(n0 + (i1 >> 2)) * K + (i1 & 3) * 8;
    ushort* lA0 = &As[i0 * 8];
    ushort* lA1 = &As[i1 * 8];
    ushort* lB0 = &Bs[i0 * 8];
    ushort* lB1 = &Bs[i1 * 8];

    f32x4 acc[4][4] = {};

    for (int k0 = 0; k0 < K; k0 += BK) {
        __builtin_amdgcn_global_load_lds((GV*)gA0, (LV*)lA0, 16, 0, 0);
        __builtin_amdgcn_global_load_lds((GV*)gA1, (LV*)lA1, 16, 0, 0);
        __builtin_amdgcn_global_load_lds((GV*)gB0, (LV*)lB0, 16, 0, 0);
        __builtin_amdgcn_global_load_lds((GV*)gB1, (LV*)lB1, 16, 0, 0);
        gA0 += BK; gA1 += BK; gB0 += BK; gB1 += BK;
        __syncthreads();

        short8 a[4], b[4];
#pragma unroll
        for (int i = 0; i < 4; ++i) {
            a[i] = *(const short8*)&As[(wm + i * 16 + lrow) * BK + quad * 8];
            b[i] = *(const short8*)&Bs[(wn + i * 16 + lrow) * BK + quad * 8];
        }
#pragma unroll
        for (int mi = 0; mi < 4; ++mi)
#pragma unroll
            for (int ni = 0; ni < 4; ++ni)
                acc[mi][ni] = __builtin_amdgcn_mfma_f32_16x16x32_bf16(
                    a[mi], b[ni], acc[mi][ni], 0, 0, 0);
        __syncthreads();
    }

    // epilogue: C/D layout col=lane&15, row=quad*4+reg [m89/m91 verified]
#pragma unroll
    for (int mi = 0; mi < 4; ++mi) {
#pragma unroll
        for (int ni = 0; ni < 4; ++ni) {
            const int gn = n0 + wn + ni * 16 + lrow;
            const float bv = be[gn];
#pragma unroll
            for (int r = 0; r < 4; ++r) {
                const int gm = m0 + wm + mi * 16 + quad * 4 + r;
                float v = acc[mi][ni][r] + bv;
                if (RELU_BF16_OUT) {
                    v = fmaxf(v, 0.f);
                    ((ushort*)out)[(size_t)e * Crows * N + (size_t)gm * N + gn] =
                        f2bf_rne(v);
                } else {
                    ((float*)out)[(size_t)e * Crows * N + (size_t)gm * N + gn] = v;
                }
            }
        }
    }
}

extern "C" void kernel_launch(void* const* d_in, const int* in_sizes, int n_in,
                              void* d_out, int out_size, void* d_ws, size_t ws_size,
                              hipStream_t stream) {
    const int E = 8, C = 4096, M = 1024, H = 4096, O = 1024;
    const float* x  = (const float*)d_in[0];
    const float* w1 = (const float*)d_in[1];
    const float* b1 = (const float*)d_in[2];
    const float* w2 = (const float*)d_in[3];
    const float* b2 = (const float*)d_in[4];
    float* out = (float*)d_out;

    // workspace: [x_bf 67MB][w1t 67MB][y 268MB]; w2t aliases w1t (used after GEMM1)
    ushort* x_bf = (ushort*)d_ws;                       // E*C*M
    ushort* w1t  = x_bf + (size_t)E * C * M;            // E*H*M
    ushort* w2t  = w1t;                                 // E*O*H (alias, after GEMM1)
    ushort* y_bf = w1t + (size_t)E * M * H;             // E*C*H

    const long nx = (long)E * C * M;
    convert_bf16<<<(nx / 8 + 255) / 256, 256, 0, stream>>>(x, x_bf, nx);
    transpose_convert<<<dim3(H / 64, M / 64, E), 256, 0, stream>>>(w1, w1t, M, H);
    // GEMM1: [E,4096,1024] @ [E,4096,1024]^T -> y [E,4096,4096] bf16, relu+bias
    gemm_bt<true, 32, 32, 1024, 4096><<<32 * 32 * 8, 256, 0, stream>>>(
        x_bf, w1t, b1, (void*)y_bf);
    transpose_convert<<<dim3(O / 64, H / 64, E), 256, 0, stream>>>(w2, w2t, H, O);
    // GEMM2: [E,4096,4096] @ [E,1024,4096]^T -> out [E,4096,1024] fp32, bias
    gemm_bt<false, 8, 32, 4096, 1024><<<8 * 32 * 8, 256, 0, stream>>>(
        y_bf, w2t, b2, (void*)out);
}